// Round 9
// baseline (621.971 us; speedup 1.0000x reference)
//
#include <hip/hip_runtime.h>

typedef __bf16 bf16x8 __attribute__((ext_vector_type(8)));
typedef float  f32x4  __attribute__((ext_vector_type(4)));
typedef unsigned short u16;

__device__ __forceinline__ u16 f2bf(float f) {
  unsigned u = __builtin_bit_cast(unsigned, f);
  u += 0x7fffu + ((u >> 16) & 1u);           // round-to-nearest-even
  return (u16)(u >> 16);
}
__device__ __forceinline__ float bf2f(u16 h) {
  return __builtin_bit_cast(float, (unsigned)h << 16);
}

using gvoid = __attribute__((address_space(1))) void;
using svoid = __attribute__((address_space(3))) void;
__device__ __forceinline__ void load_lds16(const u16* g, char* s) {
  __builtin_amdgcn_global_load_lds((const gvoid*)g, (svoid*)s, 16, 0, 0);
}

// ---------- prep: transpose+cvt F (z<8, fused passthrough) | weights f32->bf16 (z>=8) ----
__global__ void prep(const float* __restrict__ Fr, const float* __restrict__ Fi,
                     u16* __restrict__ FTr, u16* __restrict__ FTi,
                     float* __restrict__ Or, float* __restrict__ Oi,
                     const float* __restrict__ s0, const float* __restrict__ s1,
                     const float* __restrict__ s2, const float* __restrict__ s3,
                     const float* __restrict__ s4, const float* __restrict__ s5,
                     u16* __restrict__ Wall) {
  const int tx = threadIdx.x, ty = threadIdx.y;
  if (blockIdx.z >= 8) {
    // weight conversion: 12 z-slices x 2048 blocks = 24576 virtual blocks
    const int gi = (blockIdx.z - 8) * 2048 + blockIdx.y * 32 + blockIdx.x;
    const int chunk = gi >> 12;                         // 6 chunks x 4096 blocks
    const int i = (gi & 4095) * 256 + ty * 32 + tx;     // quad index in chunk
    const float* src;
    switch (chunk) {
      case 0: src = s0; break; case 1: src = s1; break; case 2: src = s2; break;
      case 3: src = s3; break; case 4: src = s4; break; default: src = s5; break;
    }
    float4 v = ((const float4*)src)[i];
    ushort4 o;
    o.x = f2bf(v.x); o.y = f2bf(v.y); o.z = f2bf(v.z); o.w = f2bf(v.w);
    ((ushort4*)(Wall + (long)chunk * 4194304))[i] = o;
    return;
  }
  __shared__ float tile[32][33];
  const int b = blockIdx.z & 3;
  const bool ind = (blockIdx.z >= 4);
  const float* F = ind ? Fi : Fr;
  u16* FT = ind ? FTi : FTr;
  float* O = ind ? Oi : Or;
  const int n0 = blockIdx.x * 32, c0 = blockIdx.y * 32;
  const long boff = (long)b * 2048 * 1024;
  const float* Fb = F + boff;
  float* Ob = O + boff;
  u16* FTb = FT + (long)b * 1024 * 2048;
#pragma unroll
  for (int i = 0; i < 4; ++i) {
    const long idx = (long)(c0 + ty + i * 8) * 1024 + n0 + tx;
    float v = Fb[idx];
    tile[ty + i * 8][tx] = v;
    Ob[idx] = v;                                  // identity passthrough (fused)
  }
  __syncthreads();
#pragma unroll
  for (int i = 0; i < 4; ++i)
    FTb[(long)(n0 + ty + i * 8) * 2048 + c0 + tx] = f2bf(tile[tx][ty + i * 8]);
}

// ================= 256x256 4-phase bf16 GEMM: D[m][n] = A[m][k]*B[n][k] =================
// R9: R7's proven schedule (4 phases / 2 K-tiles, one barrier/phase, vmcnt(6) gates at
// P1v/P1w, setprio MFMA, XCD-chunked swizzle) + pointer-stream addressing with ZERO
// global_load_lds immediates (R8's imm-offset semantics were unverified and broke
// correctness). 8 lane-dependent row pointers (A0/A1/B0/B1 x lo/hi), each staged twice
// per iter and advanced +64 elements after each use -- reproduces R7's tile sequence
// exactly (site1: A1<-v+1, site2: A0/B0/B1<-v+2, site3: A1<-v+2, site4: A0/B0/B1<-v+3).
// No tail clamp: final stages over-read <= tile nt+1 (<=256 B past region edge, vetted
// in-bounds by ws layout) into slots never read again.

#define BAR_ do { asm volatile("" ::: "memory"); __builtin_amdgcn_s_barrier(); \
                  asm volatile("" ::: "memory"); } while (0)
#define SB0 __builtin_amdgcn_sched_barrier(0)
#define LGK0 asm volatile("s_waitcnt lgkmcnt(0)" ::: "memory")
#define VMW6 asm volatile("s_waitcnt vmcnt(6)" ::: "memory")

// LDS slot byte offsets
#define b0A0 0
#define b0A1 16384
#define b0B0 32768
#define b0B1 49152
#define b1A0 65536
#define b1A1 81920
#define b1B0 98304
#define b1B1 114688

// stage one [128][64] half-tile slot from row-block pointer pair (lo/hi)
#define STG(pl, ph, off)                                                           \
  do {                                                                             \
    load_lds16(pl, sm + (off) + w * 1024);                                         \
    load_lds16(ph, sm + (off) + 8192 + w * 1024);                                  \
  } while (0)

#define RDA(off)                                                                   \
  _Pragma("unroll") for (int fm = 0; fm < 4; ++fm)                                 \
  _Pragma("unroll") for (int ks = 0; ks < 2; ++ks)                                 \
    fa[fm][ks] = *(const bf16x8*)(sm + (off) + aoff[fm] + kin[ks]);

#define RDB(off, dst)                                                              \
  _Pragma("unroll") for (int fn = 0; fn < 2; ++fn)                                 \
  _Pragma("unroll") for (int ks = 0; ks < 2; ++ks)                                 \
    dst[fn][ks] = *(const bf16x8*)(sm + (off) + boff[fn] + kin[ks]);

// 32-MFMA cluster; ks-outer + distinct acc targets -> dep distance 16
#define MMQ2(qa)                                                                   \
  __builtin_amdgcn_s_setprio(1);                                                   \
  _Pragma("unroll") for (int ks = 0; ks < 2; ++ks)                                 \
  _Pragma("unroll") for (int fm = 0; fm < 4; ++fm) {                               \
    _Pragma("unroll") for (int fn = 0; fn < 2; ++fn)                               \
      acc[qa][0][fm][fn] = __builtin_amdgcn_mfma_f32_16x16x32_bf16(                \
          fa[fm][ks], fb0[fn][ks], acc[qa][0][fm][fn], 0, 0, 0);                   \
    _Pragma("unroll") for (int fn = 0; fn < 2; ++fn)                               \
      acc[qa][1][fm][fn] = __builtin_amdgcn_mfma_f32_16x16x32_bf16(                \
          fa[fm][ks], fb1[fn][ks], acc[qa][1][fm][fn], 0, 0, 0);                   \
  }                                                                                \
  __builtin_amdgcn_s_setprio(0);

template <int OUT_BF16, int BIAS_MODE, int KSPLIT>   // BIAS: 0 none, 1 col(split@2048), 2 row
__global__ __launch_bounds__(512, 2) void gemm256(
    const u16* __restrict__ A0p, const u16* __restrict__ B0p, void* __restrict__ D0p,
    const float* __restrict__ ba0, const float* __restrict__ bb0,
    const u16* __restrict__ A1p, const u16* __restrict__ B1p, void* __restrict__ D1p,
    const float* __restrict__ ba1, const float* __restrict__ bb1,
    long sKH, int zsplit, int K, int lda, int ldb, int ldd,
    long sA, long sB, long sD) {
  __shared__ __attribute__((aligned(128))) char sm[131072];
  // XCD-chunked swizzle (T1): bijective since nwg % 8 == 0 for all our launches.
  const int gx = gridDim.x, gy = gridDim.y;
  const int nwg = gx * gy * (int)gridDim.z;
  const int lin = blockIdx.x + gx * (blockIdx.y + gy * blockIdx.z);
  const int qch = nwg >> 3;
  int swzid = (lin & 7) * qch + (lin >> 3);
  const int bx = swzid % gx; swzid /= gx;
  const int by = swzid % gy;
  int zb = swzid / gy;
  int kh = 0;
  if (KSPLIT) { kh = zb >> 3; zb &= 7; }
  const bool s1 = (zb >= zsplit);
  const int zz = s1 ? zb - zsplit : zb;
  const u16* Ag = (s1 ? A1p : A0p) + (long)zz * sA + (long)kh * K;
  const u16* Bg = (s1 ? B1p : B0p) + (long)zz * sB + (long)kh * K;
  char* Dg = (char*)(s1 ? D1p : D0p) + (long)zz * sD * (OUT_BF16 ? 2 : 4)
           + (KSPLIT ? (long)kh * sKH : 0L);
  const float* ba = s1 ? ba1 : ba0;
  const float* bb = s1 ? bb1 : bb0;
  const int m0 = by * 256, n0 = bx * 256;
  const int t = threadIdx.x, w = t >> 6, l = t & 63;
  const int wr = w >> 2, wc = w & 3;             // 2x4 waves within a quadrant
  const int lm = l & 15, lk = l >> 4;
  const int swz = (l & 7) << 4;                  // read-side XOR: (row&7)<<4
  const int srow = l >> 3;
  const int scol = ((l & 7) ^ srow) << 3;        // inverse-swizzled source col (elems)
  int aoff[4], boff[2], kin[2];
#pragma unroll
  for (int fm = 0; fm < 4; ++fm) aoff[fm] = (wr * 64 + fm * 16 + lm) * 128;
#pragma unroll
  for (int fn = 0; fn < 2; ++fn) boff[fn] = (wc * 32 + fn * 16 + lm) * 128;
  kin[0] = (lk * 16) ^ swz;
  kin[1] = (64 + lk * 16) ^ swz;

  // pointer streams (lane-dependent rows, start at tile 0)
  const u16* a0l = Ag + (long)(m0 +       w * 8 + srow) * lda + scol;
  const u16* a0h = a0l + (long)64  * lda;
  const u16* a1l = a0l + (long)128 * lda;
  const u16* a1h = a0l + (long)192 * lda;
  const u16* b0l = Bg + (long)(n0 +       w * 8 + srow) * ldb + scol;
  const u16* b0h = b0l + (long)64  * ldb;
  const u16* b1l = b0l + (long)128 * ldb;
  const u16* b1h = b0l + (long)192 * ldb;

  f32x4 acc[2][2][4][2] = {};
  bf16x8 fa[4][2], fb0[2][2], fb1[2][2];

  const int nt = K >> 6;                         // K-tiles of 64 (even for all our K)

  // prologue: tile 0 full (buf0) + tile 1 A0/B0/B1 (buf1); force buf0, keep 6 in flight
  STG(a0l, a0h, b0A0);
  STG(b0l, b0h, b0B0);
  STG(b1l, b1h, b0B1);
  STG(a1l, a1h, b0A1);
  STG(a0l + 64, a0h + 64, b1A0);
  STG(b0l + 64, b0h + 64, b1B0);
  STG(b1l + 64, b1h + 64, b1B1);
  VMW6;
  BAR_;
  // init streams: A1 -> tile 1 (site1); A0/B0/B1 -> tile 2 (site2)
  a1l += 64;  a1h += 64;
  a0l += 128; a0h += 128;
  b0l += 128; b0h += 128;
  b1l += 128; b1h += 128;

  for (int v = 0; v < nt; v += 2) {
    // P0v: tile v, quadrant-row 0. site1: b1A1 <- tile v+1.
    STG(a1l, a1h, b1A1); a1l += 64; a1h += 64;
    RDA(b0A0); RDB(b0B0, fb0); RDB(b0B1, fb1);
    BAR_; LGK0; SB0; MMQ2(0);
    // P1v: site2: b0A0/B0/B1 <- tile v+2; gate.
    STG(a0l, a0h, b0A0); a0l += 64; a0h += 64;
    STG(b0l, b0h, b0B0); b0l += 64; b0h += 64;
    STG(b1l, b1h, b0B1); b1l += 64; b1h += 64;
    RDA(b0A1);
    VMW6;
    BAR_; LGK0; SB0; MMQ2(1);
    // P0w: tile v+1, quadrant-row 0. site3: b0A1 <- tile v+2.
    STG(a1l, a1h, b0A1); a1l += 64; a1h += 64;
    RDA(b1A0); RDB(b1B0, fb0); RDB(b1B1, fb1);
    BAR_; LGK0; SB0; MMQ2(0);
    // P1w: site4: b1A0/B0/B1 <- tile v+3; gate.
    STG(a0l, a0h, b1A0); a0l += 64; a0h += 64;
    STG(b0l, b0h, b1B0); b0l += 64; b0h += 64;
    STG(b1l, b1h, b1B1); b1l += 64; b1h += 64;
    RDA(b1A1);
    VMW6;
    BAR_; LGK0; SB0; MMQ2(1);
  }

  // epilogue: C/D map col=lane&15, row=(lane>>4)*4+j (verified m89)
#pragma unroll
  for (int qa = 0; qa < 2; ++qa)
#pragma unroll
    for (int qb = 0; qb < 2; ++qb)
#pragma unroll
      for (int fm = 0; fm < 4; ++fm)
#pragma unroll
        for (int fn = 0; fn < 2; ++fn) {
          const int row0 = m0 + qa * 128 + wr * 64 + fm * 16 + lk * 4;
          const int col  = n0 + qb * 128 + wc * 32 + fn * 16 + lm;
          float cb = 0.f;
          if (BIAS_MODE == 1) cb = (col < 2048) ? ba[col] : bb[col - 2048];
          f32x4 vv = acc[qa][qb][fm][fn];
#pragma unroll
          for (int j = 0; j < 4; ++j) {
            float x = vv[j] + cb;
            if (BIAS_MODE == 2) x += ba[row0 + j];
            const long idx = (long)(row0 + j) * ldd + col;
            if (OUT_BF16) ((u16*)Dg)[idx] = f2bf(x);
            else          ((float*)Dg)[idx] = x;
          }
        }
}

// ---------- row softmax over bf16 S0+S1: softmax(alpha*(s0+s1)) -> P bf16 ----------
__global__ void softmax_rows2(const u16* __restrict__ S0, const u16* __restrict__ S1,
                              u16* __restrict__ P, float alpha) {
  const long row = blockIdx.x;
  const int t = threadIdx.x, l = t & 63, w = t >> 6;
  ushort4 a = ((const ushort4*)(S0 + row * 1024))[t];
  ushort4 b = ((const ushort4*)(S1 + row * 1024))[t];
  float v0 = bf2f(a.x) + bf2f(b.x);
  float v1 = bf2f(a.y) + bf2f(b.y);
  float v2 = bf2f(a.z) + bf2f(b.z);
  float v3 = bf2f(a.w) + bf2f(b.w);
  __shared__ float red[8];
  float m = fmaxf(fmaxf(v0, v1), fmaxf(v2, v3));
#pragma unroll
  for (int off = 32; off; off >>= 1) m = fmaxf(m, __shfl_xor(m, off));
  if (l == 0) red[w] = m;
  __syncthreads();
  m = fmaxf(fmaxf(red[0], red[1]), fmaxf(red[2], red[3]));
  float e0 = __expf((v0 - m) * alpha);
  float e1 = __expf((v1 - m) * alpha);
  float e2 = __expf((v2 - m) * alpha);
  float e3 = __expf((v3 - m) * alpha);
  float s = e0 + e1 + e2 + e3;
#pragma unroll
  for (int off = 32; off; off >>= 1) s += __shfl_xor(s, off);
  if (l == 0) red[4 + w] = s;
  __syncthreads();
  s = red[4] + red[5] + red[6] + red[7];
  const float inv = 1.0f / s;
  ushort4 o;
  o.x = f2bf(e0 * inv); o.y = f2bf(e1 * inv);
  o.z = f2bf(e2 * inv); o.w = f2bf(e3 * inv);
  ((ushort4*)(P + row * 1024))[t] = o;
}

// ---------- F_final = AW[b][0] + AW[b][1] ----------
__global__ void final_add(const float4* __restrict__ aw, float4* __restrict__ dst) {
  const long i = (long)blockIdx.x * 256 + threadIdx.x;  // 2,097,152 quads
  const long b = i >> 19;
  const long r = i & 524287;
  float4 a = aw[b * 1048576 + r];
  float4 c = aw[b * 1048576 + 524288 + r];
  float4 o;
  o.x = a.x + c.x; o.y = a.y + c.y; o.z = a.z + c.z; o.w = a.w + c.w;
  dst[i] = o;
}

// ---------- launch ----------
extern "C" void kernel_launch(void* const* d_in, const int* in_sizes, int n_in,
                              void* d_out, int out_size, void* d_ws, size_t ws_size,
                              hipStream_t stream) {
  (void)in_sizes; (void)n_in; (void)out_size; (void)ws_size;
  const float* F_rgb = (const float*)d_in[0];
  const float* F_ind = (const float*)d_in[1];
  const float* bq_rgb = (const float*)d_in[3];
  const float* bk_rgb = (const float*)d_in[5];
  const float* bv_rgb = (const float*)d_in[7];
  const float* bq_ind = (const float*)d_in[9];
  const float* bk_ind = (const float*)d_in[11];
  const float* bv_ind = (const float*)d_in[13];

  char* ws = (char*)d_ws;
  // ws layout: every GEMM operand has a successor region (over-read <=256 B safe);
  // S0c placed LAST (read exactly by softmax only).
  u16* FT_rgb  = (u16*)(ws);                        // [4][1024][2048] bf16
  u16* FT_ind  = (u16*)(ws + 16777216);
  u16* S1c     = (u16*)(ws);                        // ALIAS: K-half-1 scores (FT dead then)
  u16* Wall    = (u16*)(ws + 33554432);             // 6x [2048][2048] bf16
  u16* Wqk_rgb = Wall;                              // [4096][2048] = Wq_rgb | Wk_rgb
  u16* Wqk_ind = (u16*)(ws + 50331648);
  u16* Wv_rgb  = (u16*)(ws + 67108864);
  u16* Wv_ind  = (u16*)(ws + 75497472);
  u16* QKT_rgb = (u16*)(ws + 83886080);             // [4][1024][4096]  Q|K
  u16* QKT_ind = (u16*)(ws + 117440512);
  u16* V_rgb   = (u16*)(ws + 150994944);            // [4][2048][1024]
  u16* V_ind   = (u16*)(ws + 167772160);
  u16* P       = (u16*)(ws + 184549376);            // [2][4][1024][1024] bf16
  u16* S0c     = (u16*)(ws + 218103808);            // [2][4][1024][1024] bf16 (LAST)

  float* out       = (float*)d_out;
  float* out_final = out;                           // [4][2048][1024]
  float* out_Frgb  = out + 8388608;
  float* out_Find  = out + 16777216;
  float* AW        = out + 25165824;                // [4][2][2048][1024]

  // 1) prep: transpose+convert inputs (+identity passthrough) AND weight conversion
  prep<<<dim3(32, 64, 20), dim3(32, 8), 0, stream>>>(
      F_rgb, F_ind, FT_rgb, FT_ind, out_Frgb, out_Find,
      (const float*)d_in[2], (const float*)d_in[4],
      (const float*)d_in[8], (const float*)d_in[10],
      (const float*)d_in[6], (const float*)d_in[12], Wall);

  // 2) fused Q|K convs, both inputs in ONE 512-WG launch (col bias, split@2048)
  gemm256<1, 1, 0><<<dim3(16, 4, 8), 512, 0, stream>>>(
      FT_rgb, Wqk_rgb, QKT_rgb, bq_rgb, bk_rgb,
      FT_ind, Wqk_ind, QKT_ind, bq_ind, bk_ind,
      0L, 4, 2048, 2048, 2048, 4096, 2097152L, 0L, 4194304L);

  // 3) V convs (both inputs): V[c][n] = sum_k Wv[c][k] FT[n][k] + b[c]  (row bias)
  gemm256<1, 2, 0><<<dim3(4, 8, 8), 512, 0, stream>>>(
      Wv_rgb, FT_rgb, V_rgb, bv_rgb, bv_rgb,
      Wv_ind, FT_ind, V_ind, bv_ind, bv_ind,
      0L, 4, 2048, 2048, 2048, 1024, 0L, 2097152L, 2097152L);

  // 4) scores split-K x2 -> bf16 S0 (kh=0) / S1 (kh=1), no atomics
  gemm256<1, 0, 1><<<dim3(4, 4, 16), 512, 0, stream>>>(
      QKT_rgb, QKT_ind + 2048, S0c, nullptr, nullptr,
      QKT_ind, QKT_rgb + 2048, S0c + 4194304, nullptr, nullptr,
      (long)((char*)S1c - (char*)S0c), 4, 1024, 4096, 4096, 1024,
      4194304L, 4194304L, 1048576L);

  // 5) softmax over S0+S1 (scale 1/sqrt(2048) folded in)
  softmax_rows2<<<8192, 256, 0, stream>>>(S0c, S1c, P, 0.02209708691207961f);

  // 6) PV (both directions): AW[c][n] = sum_m V[c][m] P[n][m]  (plain stores)
  gemm256<0, 0, 0><<<dim3(4, 8, 8), 512, 0, stream>>>(
      V_ind, P, AW, nullptr, nullptr,
      V_rgb, P + 4194304, AW + 2097152, nullptr, nullptr,
      0L, 4, 1024, 1024, 1024, 1024, 2097152L, 1048576L, 4194304L);

  // 7) F_final = AW0 + AW1
  final_add<<<8192, 256, 0, stream>>>((const float4*)AW, (float4*)out_final);
}

// Round 10
// 364.431 us; speedup vs baseline: 1.7067x; 1.7067x over previous
//
#include <hip/hip_runtime.h>

typedef __bf16 bf16x8 __attribute__((ext_vector_type(8)));
typedef float  f32x4  __attribute__((ext_vector_type(4)));
typedef unsigned short u16;

__device__ __forceinline__ u16 f2bf(float f) {
  unsigned u = __builtin_bit_cast(unsigned, f);
  u += 0x7fffu + ((u >> 16) & 1u);           // round-to-nearest-even
  return (u16)(u >> 16);
}
__device__ __forceinline__ float bf2f(u16 h) {
  return __builtin_bit_cast(float, (unsigned)h << 16);
}

using gvoid = __attribute__((address_space(1))) void;
using svoid = __attribute__((address_space(3))) void;
__device__ __forceinline__ void load_lds16(const void* g, void* s) {
  __builtin_amdgcn_global_load_lds((const gvoid*)g, (svoid*)s, 16, 0, 0);
}

// ---------- prep: transpose+cvt F (z<8, fused passthrough) | weights f32->bf16 (z>=8) ----
__global__ void prep(const float* __restrict__ Fr, const float* __restrict__ Fi,
                     u16* __restrict__ FTr, u16* __restrict__ FTi,
                     float* __restrict__ Or, float* __restrict__ Oi,
                     const float* __restrict__ s0, const float* __restrict__ s1,
                     const float* __restrict__ s2, const float* __restrict__ s3,
                     const float* __restrict__ s4, const float* __restrict__ s5,
                     u16* __restrict__ Wall) {
  const int tx = threadIdx.x, ty = threadIdx.y;
  if (blockIdx.z >= 8) {
    const int gi = (blockIdx.z - 8) * 2048 + blockIdx.y * 32 + blockIdx.x;
    const int chunk = gi >> 12;                         // 6 chunks x 4096 blocks
    const int i = (gi & 4095) * 256 + ty * 32 + tx;     // quad index in chunk
    const float* src;
    switch (chunk) {
      case 0: src = s0; break; case 1: src = s1; break; case 2: src = s2; break;
      case 3: src = s3; break; case 4: src = s4; break; default: src = s5; break;
    }
    float4 v = ((const float4*)src)[i];
    ushort4 o;
    o.x = f2bf(v.x); o.y = f2bf(v.y); o.z = f2bf(v.z); o.w = f2bf(v.w);
    ((ushort4*)(Wall + (long)chunk * 4194304))[i] = o;
    return;
  }
  __shared__ float tile[32][33];
  const int b = blockIdx.z & 3;
  const bool ind = (blockIdx.z >= 4);
  const float* F = ind ? Fi : Fr;
  u16* FT = ind ? FTi : FTr;
  float* O = ind ? Oi : Or;
  const int n0 = blockIdx.x * 32, c0 = blockIdx.y * 32;
  const long boff = (long)b * 2048 * 1024;
  const float* Fb = F + boff;
  float* Ob = O + boff;
  u16* FTb = FT + (long)b * 1024 * 2048;
#pragma unroll
  for (int i = 0; i < 4; ++i) {
    const long idx = (long)(c0 + ty + i * 8) * 1024 + n0 + tx;
    float v = Fb[idx];
    tile[ty + i * 8][tx] = v;
    Ob[idx] = v;                                  // identity passthrough (fused)
  }
  __syncthreads();
#pragma unroll
  for (int i = 0; i < 4; ++i)
    FTb[(long)(n0 + ty + i * 8) * 2048 + c0 + tx] = f2bf(tile[tx][ty + i * 8]);
}

// ================= 256x256 4-phase bf16 GEMM (R7-exact): D[m][n]=A[m][k]*B[n][k] =======
// Used for the big convs (QK: 512 WGs; V: 256 WGs). Schedule: 4 phases / 2 K-tiles,
// one barrier per phase, vmcnt(6) gates at P1v/P1w, setprio MFMA, XCD-chunked swizzle.

#define BAR_ do { asm volatile("" ::: "memory"); __builtin_amdgcn_s_barrier(); \
                  asm volatile("" ::: "memory"); } while (0)
#define SB0 __builtin_amdgcn_sched_barrier(0)
#define LGK0 asm volatile("s_waitcnt lgkmcnt(0)" ::: "memory")
#define VMW6 asm volatile("s_waitcnt vmcnt(6)" ::: "memory")

// LDS slot byte offsets
#define b0A0 0
#define b0A1 16384
#define b0B0 32768
#define b0B1 49152
#define b1A0 65536
#define b1A1 81920
#define b1B0 98304
#define b1B1 114688

#define STG(Mp, ld, row0, kt, off)                                                 \
  do {                                                                             \
    load_lds16(Mp + (long)((row0) + w * 8 + srow) * (ld) + (kt) * 64 + scol,       \
               sm + (off) + w * 1024);                                             \
    load_lds16(Mp + (long)((row0) + 64 + w * 8 + srow) * (ld) + (kt) * 64 + scol,  \
               sm + (off) + 8192 + w * 1024);                                      \
  } while (0)

#define RDA(off)                                                                   \
  _Pragma("unroll") for (int fm = 0; fm < 4; ++fm)                                 \
  _Pragma("unroll") for (int ks = 0; ks < 2; ++ks)                                 \
    fa[fm][ks] = *(const bf16x8*)(sm + (off) + aoff[fm] + kin[ks]);

#define RDB(off, dst)                                                              \
  _Pragma("unroll") for (int fn = 0; fn < 2; ++fn)                                 \
  _Pragma("unroll") for (int ks = 0; ks < 2; ++ks)                                 \
    dst[fn][ks] = *(const bf16x8*)(sm + (off) + boff[fn] + kin[ks]);

#define MMQ2(qa)                                                                   \
  __builtin_amdgcn_s_setprio(1);                                                   \
  _Pragma("unroll") for (int ks = 0; ks < 2; ++ks)                                 \
  _Pragma("unroll") for (int fm = 0; fm < 4; ++fm) {                               \
    _Pragma("unroll") for (int fn = 0; fn < 2; ++fn)                               \
      acc[qa][0][fm][fn] = __builtin_amdgcn_mfma_f32_16x16x32_bf16(                \
          fa[fm][ks], fb0[fn][ks], acc[qa][0][fm][fn], 0, 0, 0);                   \
    _Pragma("unroll") for (int fn = 0; fn < 2; ++fn)                               \
      acc[qa][1][fm][fn] = __builtin_amdgcn_mfma_f32_16x16x32_bf16(                \
          fa[fm][ks], fb1[fn][ks], acc[qa][1][fm][fn], 0, 0, 0);                   \
  }                                                                                \
  __builtin_amdgcn_s_setprio(0);

template <int OUT_BF16, int BIAS_MODE, int KSPLIT>   // BIAS: 0 none, 1 col(split@2048), 2 row
__global__ __launch_bounds__(512, 2) void gemm256(
    const u16* __restrict__ A0p, const u16* __restrict__ B0p, void* __restrict__ D0p,
    const float* __restrict__ ba0, const float* __restrict__ bb0,
    const u16* __restrict__ A1p, const u16* __restrict__ B1p, void* __restrict__ D1p,
    const float* __restrict__ ba1, const float* __restrict__ bb1,
    long sKH, int zsplit, int K, int lda, int ldb, int ldd,
    long sA, long sB, long sD) {
  __shared__ __attribute__((aligned(128))) char sm[131072];
  // XCD-chunked swizzle (T1): bijective since nwg % 8 == 0 for all our launches.
  const int gx = gridDim.x, gy = gridDim.y;
  const int nwg = gx * gy * (int)gridDim.z;
  const int lin = blockIdx.x + gx * (blockIdx.y + gy * blockIdx.z);
  const int qch = nwg >> 3;
  int swzid = (lin & 7) * qch + (lin >> 3);
  const int bx = swzid % gx; swzid /= gx;
  const int by = swzid % gy;
  int zb = swzid / gy;
  int kh = 0;
  if (KSPLIT) { kh = zb >> 3; zb &= 7; }
  const bool s1 = (zb >= zsplit);
  const int zz = s1 ? zb - zsplit : zb;
  const u16* Ag = (s1 ? A1p : A0p) + (long)zz * sA + (long)kh * K;
  const u16* Bg = (s1 ? B1p : B0p) + (long)zz * sB + (long)kh * K;
  char* Dg = (char*)(s1 ? D1p : D0p) + (long)zz * sD * (OUT_BF16 ? 2 : 4)
           + (KSPLIT ? (long)kh * sKH : 0L);
  const float* ba = s1 ? ba1 : ba0;
  const float* bb = s1 ? bb1 : bb0;
  const int m0 = by * 256, n0 = bx * 256;
  const int t = threadIdx.x, w = t >> 6, l = t & 63;
  const int wr = w >> 2, wc = w & 3;             // 2x4 waves within a quadrant
  const int lm = l & 15, lk = l >> 4;
  const int swz = (l & 7) << 4;                  // read-side XOR: (row&7)<<4
  const int srow = l >> 3;
  const int scol = ((l & 7) ^ srow) << 3;        // inverse-swizzled source col (elems)
  int aoff[4], boff[2], kin[2];
#pragma unroll
  for (int fm = 0; fm < 4; ++fm) aoff[fm] = (wr * 64 + fm * 16 + lm) * 128;
#pragma unroll
  for (int fn = 0; fn < 2; ++fn) boff[fn] = (wc * 32 + fn * 16 + lm) * 128;
  kin[0] = (lk * 16) ^ swz;
  kin[1] = (64 + lk * 16) ^ swz;

  f32x4 acc[2][2][4][2] = {};
  bf16x8 fa[4][2], fb0[2][2], fb1[2][2];

  const int nt = K >> 6;                         // K-tiles of 64 (even for all our K)

  // prologue: buf0 full + b1A0,b1B0,b1B1; force buf0 (8 oldest), keep 6 in flight
  STG(Ag, lda, m0,       0, b0A0);
  STG(Bg, ldb, n0,       0, b0B0);
  STG(Bg, ldb, n0 + 128, 0, b0B1);
  STG(Ag, lda, m0 + 128, 0, b0A1);
  STG(Ag, lda, m0,       1, b1A0);
  STG(Bg, ldb, n0,       1, b1B0);
  STG(Bg, ldb, n0 + 128, 1, b1B1);
  VMW6;
  BAR_;

  for (int v = 0; v < nt; v += 2) {
    const int t2 = (v + 2 < nt) ? v + 2 : nt - 1;   // clamped (redundant tail restage ok)
    const int t3 = (v + 3 < nt) ? v + 3 : nt - 1;
    // P0v: tile v, quadrant-row 0
    STG(Ag, lda, m0 + 128, v + 1, b1A1);            // completes buf1 (read @P1w)
    RDA(b0A0); RDB(b0B0, fb0); RDB(b0B1, fb1);
    BAR_; LGK0; SB0; MMQ2(0);
    // P1v: tile v, quadrant-row 1 (fb0/fb1 persist); gate forces b1A1 + older
    STG(Ag, lda, m0, t2, b0A0);
    STG(Bg, ldb, n0, t2, b0B0);
    STG(Bg, ldb, n0 + 128, t2, b0B1);
    RDA(b0A1);
    VMW6;
    BAR_; LGK0; SB0; MMQ2(1);
    // P0w: tile v+1, quadrant-row 0
    STG(Ag, lda, m0 + 128, t2, b0A1);
    RDA(b1A0); RDB(b1B0, fb0); RDB(b1B1, fb1);
    BAR_; LGK0; SB0; MMQ2(0);
    // P1w: tile v+1, quadrant-row 1; gate forces b0A1(t2) + older
    STG(Ag, lda, m0, t3, b1A0);
    STG(Bg, ldb, n0, t3, b1B0);
    STG(Bg, ldb, n0 + 128, t3, b1B1);
    RDA(b1A1);
    VMW6;
    BAR_; LGK0; SB0; MMQ2(1);
  }

  // epilogue: C/D map col=lane&15, row=(lane>>4)*4+j (verified m89)
#pragma unroll
  for (int qa = 0; qa < 2; ++qa)
#pragma unroll
    for (int qb = 0; qb < 2; ++qb)
#pragma unroll
      for (int fm = 0; fm < 4; ++fm)
#pragma unroll
        for (int fn = 0; fn < 2; ++fn) {
          const int row0 = m0 + qa * 128 + wr * 64 + fm * 16 + lk * 4;
          const int col  = n0 + qb * 128 + wc * 32 + fn * 16 + lm;
          float cb = 0.f;
          if (BIAS_MODE == 1) cb = (col < 2048) ? ba[col] : bb[col - 2048];
          f32x4 vv = acc[qa][qb][fm][fn];
#pragma unroll
          for (int j = 0; j < 4; ++j) {
            float x = vv[j] + cb;
            if (BIAS_MODE == 2) x += ba[row0 + j];
            const long idx = (long)(row0 + j) * ldd + col;
            if (OUT_BF16) ((u16*)Dg)[idx] = f2bf(x);
            else          ((float*)Dg)[idx] = x;
          }
        }
}

// ================= 128x128 bf16 GEMM (m97-class, 32 KiB LDS, 4-5 WGs/CU) ===============
// For the occupancy-starved attention GEMMs (scores, PV): 1024-WG grids, cross-WG
// overlap hides the per-K-step vmcnt(0) drain (m97/m114 mechanism). Core is the R1
// kernel that validated end-to-end (same swizzle family as gemm256).
template <int OUT_BF16, int KSPLIT>
__global__ __launch_bounds__(256) void gemm128(
    const u16* __restrict__ A0p, const u16* __restrict__ B0p, void* __restrict__ D0p,
    const u16* __restrict__ A1p, const u16* __restrict__ B1p, void* __restrict__ D1p,
    long sKH, int zsplit, int K, int lda, int ldb, int ldd,
    long sA, long sB, long sD) {
  __shared__ __attribute__((aligned(128))) char sm[32768];
  char* sA_ = sm;
  char* sB_ = sm + 16384;
  int zb = blockIdx.z;
  int kh = 0;
  if (KSPLIT) { kh = zb >> 3; zb &= 7; }
  const bool s1 = (zb >= zsplit);
  const int zz = s1 ? zb - zsplit : zb;
  const u16* Ab = (s1 ? A1p : A0p) + (long)zz * sA + (long)kh * K;
  const u16* Bb = (s1 ? B1p : B0p) + (long)zz * sB + (long)kh * K;
  char* Dg = (char*)(s1 ? D1p : D0p) + (long)zz * sD * (OUT_BF16 ? 2 : 4)
           + (KSPLIT ? (long)kh * sKH : 0L);
  const int m0 = blockIdx.y * 128, n0 = blockIdx.x * 128;
  const int t = threadIdx.x;
  const int w = t >> 6, l = t & 63;
  const int wm = w >> 1, wn = w & 1;
  const int lhi = l >> 4, llo = l & 15;
  const int srow = l >> 3;
  const int scolb = (((l & 7) ^ srow) << 4);     // inverse-swizzled source col (BYTES)
  const int swz = (l & 7) << 4;                  // read-side XOR (row&7)<<4
  f32x4 acc[4][4] = {};
  int abase[4], bbase[4];
#pragma unroll
  for (int f = 0; f < 4; ++f) {
    abase[f] = (wm * 64 + f * 16 + llo) * 128;
    bbase[f] = (wn * 64 + f * 16 + llo) * 128;
  }
  const int in0 = (0 * 64 + lhi * 16) ^ swz;
  const int in1 = (1 * 64 + lhi * 16) ^ swz;

  for (int k0 = 0; k0 < K; k0 += 64) {
#pragma unroll
    for (int i = 0; i < 4; ++i) {
      const int ci = i * 4 + w;                  // 16 chunks of 8 rows
      const int row = ci * 8 + srow;
      load_lds16((const char*)(Ab + (long)(m0 + row) * lda + k0) + scolb,
                 sA_ + ci * 1024);
      load_lds16((const char*)(Bb + (long)(n0 + row) * ldb + k0) + scolb,
                 sB_ + ci * 1024);
    }
    asm volatile("s_waitcnt vmcnt(0)" ::: "memory");
    __syncthreads();
#pragma unroll
    for (int ks = 0; ks < 2; ++ks) {
      const int inner = ks ? in1 : in0;
      bf16x8 af[4], bfr[4];
#pragma unroll
      for (int f = 0; f < 4; ++f) {
        af[f]  = *(const bf16x8*)(sA_ + abase[f] + inner);
        bfr[f] = *(const bf16x8*)(sB_ + bbase[f] + inner);
      }
#pragma unroll
      for (int fm = 0; fm < 4; ++fm)
#pragma unroll
        for (int fn = 0; fn < 4; ++fn)
          acc[fm][fn] = __builtin_amdgcn_mfma_f32_16x16x32_bf16(
              af[fm], bfr[fn], acc[fm][fn], 0, 0, 0);
    }
    __syncthreads();
  }

  // epilogue: C/D map col=lane&15, row=(lane>>4)*4+j (verified m89)
#pragma unroll
  for (int fm = 0; fm < 4; ++fm) {
    const int row = m0 + wm * 64 + fm * 16 + lhi * 4;
#pragma unroll
    for (int fn = 0; fn < 4; ++fn) {
      const int col = n0 + wn * 64 + fn * 16 + llo;
      f32x4 v = acc[fm][fn];
#pragma unroll
      for (int j = 0; j < 4; ++j) {
        const long idx = (long)(row + j) * ldd + col;
        if (OUT_BF16) ((u16*)Dg)[idx] = f2bf(v[j]);
        else          ((float*)Dg)[idx] = v[j];
      }
    }
  }
}

// ---------- row softmax over bf16 S0+S1: softmax(alpha*(s0+s1)) -> P bf16 ----------
__global__ void softmax_rows2(const u16* __restrict__ S0, const u16* __restrict__ S1,
                              u16* __restrict__ P, float alpha) {
  const long row = blockIdx.x;
  const int t = threadIdx.x, l = t & 63, w = t >> 6;
  ushort4 a = ((const ushort4*)(S0 + row * 1024))[t];
  ushort4 b = ((const ushort4*)(S1 + row * 1024))[t];
  float v0 = bf2f(a.x) + bf2f(b.x);
  float v1 = bf2f(a.y) + bf2f(b.y);
  float v2 = bf2f(a.z) + bf2f(b.z);
  float v3 = bf2f(a.w) + bf2f(b.w);
  __shared__ float red[8];
  float m = fmaxf(fmaxf(v0, v1), fmaxf(v2, v3));
#pragma unroll
  for (int off = 32; off; off >>= 1) m = fmaxf(m, __shfl_xor(m, off));
  if (l == 0) red[w] = m;
  __syncthreads();
  m = fmaxf(fmaxf(red[0], red[1]), fmaxf(red[2], red[3]));
  float e0 = __expf((v0 - m) * alpha);
  float e1 = __expf((v1 - m) * alpha);
  float e2 = __expf((v2 - m) * alpha);
  float e3 = __expf((v3 - m) * alpha);
  float s = e0 + e1 + e2 + e3;
#pragma unroll
  for (int off = 32; off; off >>= 1) s += __shfl_xor(s, off);
  if (l == 0) red[4 + w] = s;
  __syncthreads();
  s = red[4] + red[5] + red[6] + red[7];
  const float inv = 1.0f / s;
  ushort4 o;
  o.x = f2bf(e0 * inv); o.y = f2bf(e1 * inv);
  o.z = f2bf(e2 * inv); o.w = f2bf(e3 * inv);
  ((ushort4*)(P + row * 1024))[t] = o;
}

// ---------- F_final = AW[b][0] + AW[b][1] ----------
__global__ void final_add(const float4* __restrict__ aw, float4* __restrict__ dst) {
  const long i = (long)blockIdx.x * 256 + threadIdx.x;  // 2,097,152 quads
  const long b = i >> 19;
  const long r = i & 524287;
  float4 a = aw[b * 1048576 + r];
  float4 c = aw[b * 1048576 + 524288 + r];
  float4 o;
  o.x = a.x + c.x; o.y = a.y + c.y; o.z = a.z + c.z; o.w = a.w + c.w;
  dst[i] = o;
}

// ---------- launch ----------
extern "C" void kernel_launch(void* const* d_in, const int* in_sizes, int n_in,
                              void* d_out, int out_size, void* d_ws, size_t ws_size,
                              hipStream_t stream) {
  (void)in_sizes; (void)n_in; (void)out_size; (void)ws_size;
  const float* F_rgb = (const float*)d_in[0];
  const float* F_ind = (const float*)d_in[1];
  const float* bq_rgb = (const float*)d_in[3];
  const float* bk_rgb = (const float*)d_in[5];
  const float* bv_rgb = (const float*)d_in[7];
  const float* bq_ind = (const float*)d_in[9];
  const float* bk_ind = (const float*)d_in[11];
  const float* bv_ind = (const float*)d_in[13];

  char* ws = (char*)d_ws;
  u16* FT_rgb  = (u16*)(ws);                        // [4][1024][2048] bf16
  u16* FT_ind  = (u16*)(ws + 16777216);
  u16* S1c     = (u16*)(ws);                        // ALIAS: K-half-1 scores (FT dead then)
  u16* Wall    = (u16*)(ws + 33554432);             // 6x [2048][2048] bf16
  u16* Wqk_rgb = Wall;                              // [4096][2048] = Wq_rgb | Wk_rgb
  u16* Wqk_ind = (u16*)(ws + 50331648);
  u16* Wv_rgb  = (u16*)(ws + 67108864);
  u16* Wv_ind  = (u16*)(ws + 75497472);
  u16* QKT_rgb = (u16*)(ws + 83886080);             // [4][1024][4096]  Q|K
  u16* QKT_ind = (u16*)(ws + 117440512);
  u16* V_rgb   = (u16*)(ws + 150994944);            // [4][2048][1024]
  u16* V_ind   = (u16*)(ws + 167772160);
  u16* S0c     = (u16*)(ws + 184549376);            // [2][4][1024][1024] bf16
  u16* P       = (u16*)(ws + 218103808);            // [2][4][1024][1024] bf16

  float* out       = (float*)d_out;
  float* out_final = out;                           // [4][2048][1024]
  float* out_Frgb  = out + 8388608;
  float* out_Find  = out + 16777216;
  float* AW        = out + 25165824;                // [4][2][2048][1024]

  // 1) prep: transpose+convert inputs (+identity passthrough) AND weight conversion
  prep<<<dim3(32, 64, 20), dim3(32, 8), 0, stream>>>(
      F_rgb, F_ind, FT_rgb, FT_ind, out_Frgb, out_Find,
      (const float*)d_in[2], (const float*)d_in[4],
      (const float*)d_in[8], (const float*)d_in[10],
      (const float*)d_in[6], (const float*)d_in[12], Wall);

  // 2) fused Q|K convs, both inputs in ONE 512-WG launch (col bias, split@2048)
  gemm256<1, 1, 0><<<dim3(16, 4, 8), 512, 0, stream>>>(
      FT_rgb, Wqk_rgb, QKT_rgb, bq_rgb, bk_rgb,
      FT_ind, Wqk_ind, QKT_ind, bq_ind, bk_ind,
      0L, 4, 2048, 2048, 2048, 4096, 2097152L, 0L, 4194304L);

  // 3) V convs (both inputs): V[c][n] = sum_k Wv[c][k] FT[n][k] + b[c]  (row bias)
  gemm256<1, 2, 0><<<dim3(4, 8, 8), 512, 0, stream>>>(
      Wv_rgb, FT_rgb, V_rgb, bv_rgb, bv_rgb,
      Wv_ind, FT_ind, V_ind, bv_ind, bv_ind,
      0L, 4, 2048, 2048, 2048, 1024, 0L, 2097152L, 2097152L);

  // 4) scores split-K x2 -> bf16 S0 (kh=0) / S1 (kh=1); 128^2 kernel, 1024 WGs
  gemm128<1, 1><<<dim3(8, 8, 16), 256, 0, stream>>>(
      QKT_rgb, QKT_ind + 2048, S0c,
      QKT_ind, QKT_rgb + 2048, S0c + 4194304,
      (long)((char*)S1c - (char*)S0c), 4, 1024, 4096, 4096, 1024,
      4194304L, 4194304L, 1048576L);

  // 5) softmax over S0+S1 (scale 1/sqrt(2048) folded in)
  softmax_rows2<<<8192, 256, 0, stream>>>(S0c, S1c, P, 0.02209708691207961f);

  // 6) PV (both directions): AW[c][n] = sum_m V[c][m] P[n][m]; 128^2 kernel, 1024 WGs
  gemm128<0, 0><<<dim3(8, 16, 8), 256, 0, stream>>>(
      V_ind, P, AW,
      V_rgb, P + 4194304, AW + 2097152,
      0L, 4, 1024, 1024, 1024, 1024, 2097152L, 1048576L, 4194304L);

  // 7) F_final = AW0 + AW1
  final_add<<<8192, 256, 0, stream>>>((const float4*)AW, (float4*)out_final);
}

// Round 11
// 358.873 us; speedup vs baseline: 1.7331x; 1.0155x over previous
//
#include <hip/hip_runtime.h>

typedef __bf16 bf16x8 __attribute__((ext_vector_type(8)));
typedef float  f32x4  __attribute__((ext_vector_type(4)));
typedef unsigned short u16;

__device__ __forceinline__ u16 f2bf(float f) {
  unsigned u = __builtin_bit_cast(unsigned, f);
  u += 0x7fffu + ((u >> 16) & 1u);           // round-to-nearest-even
  return (u16)(u >> 16);
}
__device__ __forceinline__ float bf2f(u16 h) {
  return __builtin_bit_cast(float, (unsigned)h << 16);
}

using gvoid = __attribute__((address_space(1))) void;
using svoid = __attribute__((address_space(3))) void;
__device__ __forceinline__ void load_lds16(const void* g, void* s) {
  __builtin_amdgcn_global_load_lds((const gvoid*)g, (svoid*)s, 16, 0, 0);
}

// ---------- prep: transpose+cvt F (z<8, fused passthrough) | weights f32->bf16 (z>=8) ----
__global__ void prep(const float* __restrict__ Fr, const float* __restrict__ Fi,
                     u16* __restrict__ FTr, u16* __restrict__ FTi,
                     float* __restrict__ Or, float* __restrict__ Oi,
                     const float* __restrict__ s0, const float* __restrict__ s1,
                     const float* __restrict__ s2, const float* __restrict__ s3,
                     const float* __restrict__ s4, const float* __restrict__ s5,
                     u16* __restrict__ Wall) {
  const int tx = threadIdx.x, ty = threadIdx.y;
  if (blockIdx.z >= 8) {
    const int gi = (blockIdx.z - 8) * 2048 + blockIdx.y * 32 + blockIdx.x;
    const int chunk = gi >> 12;                         // 6 chunks x 4096 blocks
    const int i = (gi & 4095) * 256 + ty * 32 + tx;     // quad index in chunk
    const float* src;
    switch (chunk) {
      case 0: src = s0; break; case 1: src = s1; break; case 2: src = s2; break;
      case 3: src = s3; break; case 4: src = s4; break; default: src = s5; break;
    }
    float4 v = ((const float4*)src)[i];
    ushort4 o;
    o.x = f2bf(v.x); o.y = f2bf(v.y); o.z = f2bf(v.z); o.w = f2bf(v.w);
    ((ushort4*)(Wall + (long)chunk * 4194304))[i] = o;
    return;
  }
  __shared__ float tile[32][33];
  const int b = blockIdx.z & 3;
  const bool ind = (blockIdx.z >= 4);
  const float* F = ind ? Fi : Fr;
  u16* FT = ind ? FTi : FTr;
  float* O = ind ? Oi : Or;
  const int n0 = blockIdx.x * 32, c0 = blockIdx.y * 32;
  const long boff = (long)b * 2048 * 1024;
  const float* Fb = F + boff;
  float* Ob = O + boff;
  u16* FTb = FT + (long)b * 1024 * 2048;
#pragma unroll
  for (int i = 0; i < 4; ++i) {
    const long idx = (long)(c0 + ty + i * 8) * 1024 + n0 + tx;
    float v = Fb[idx];
    tile[ty + i * 8][tx] = v;
    Ob[idx] = v;                                  // identity passthrough (fused)
  }
  __syncthreads();
#pragma unroll
  for (int i = 0; i < 4; ++i)
    FTb[(long)(n0 + ty + i * 8) * 2048 + c0 + tx] = f2bf(tile[tx][ty + i * 8]);
}

// ================= 256x256 4-phase bf16 GEMM (R7-exact core): D[m][n]=A[m][k]*B[n][k] ===
// 4 phases / 2 K-tiles, one barrier per phase, vmcnt(6) gates at P1v/P1w, setprio MFMA,
// XCD-chunked swizzle. KSPLIT: kh = z>>3 selects a K-chunk of length K (param); D gets
// kh-dependent byte offset from {0, sk1, sk2, sk3} (partial buffers may be non-contiguous).

#define BAR_ do { asm volatile("" ::: "memory"); __builtin_amdgcn_s_barrier(); \
                  asm volatile("" ::: "memory"); } while (0)
#define SB0 __builtin_amdgcn_sched_barrier(0)
#define LGK0 asm volatile("s_waitcnt lgkmcnt(0)" ::: "memory")
#define VMW6 asm volatile("s_waitcnt vmcnt(6)" ::: "memory")

// LDS slot byte offsets
#define b0A0 0
#define b0A1 16384
#define b0B0 32768
#define b0B1 49152
#define b1A0 65536
#define b1A1 81920
#define b1B0 98304
#define b1B1 114688

#define STG(Mp, ld, row0, kt, off)                                                 \
  do {                                                                             \
    load_lds16(Mp + (long)((row0) + w * 8 + srow) * (ld) + (kt) * 64 + scol,       \
               sm + (off) + w * 1024);                                             \
    load_lds16(Mp + (long)((row0) + 64 + w * 8 + srow) * (ld) + (kt) * 64 + scol,  \
               sm + (off) + 8192 + w * 1024);                                      \
  } while (0)

#define RDA(off)                                                                   \
  _Pragma("unroll") for (int fm = 0; fm < 4; ++fm)                                 \
  _Pragma("unroll") for (int ks = 0; ks < 2; ++ks)                                 \
    fa[fm][ks] = *(const bf16x8*)(sm + (off) + aoff[fm] + kin[ks]);

#define RDB(off, dst)                                                              \
  _Pragma("unroll") for (int fn = 0; fn < 2; ++fn)                                 \
  _Pragma("unroll") for (int ks = 0; ks < 2; ++ks)                                 \
    dst[fn][ks] = *(const bf16x8*)(sm + (off) + boff[fn] + kin[ks]);

#define MMQ2(qa)                                                                   \
  __builtin_amdgcn_s_setprio(1);                                                   \
  _Pragma("unroll") for (int ks = 0; ks < 2; ++ks)                                 \
  _Pragma("unroll") for (int fm = 0; fm < 4; ++fm) {                               \
    _Pragma("unroll") for (int fn = 0; fn < 2; ++fn)                               \
      acc[qa][0][fm][fn] = __builtin_amdgcn_mfma_f32_16x16x32_bf16(                \
          fa[fm][ks], fb0[fn][ks], acc[qa][0][fm][fn], 0, 0, 0);                   \
    _Pragma("unroll") for (int fn = 0; fn < 2; ++fn)                               \
      acc[qa][1][fm][fn] = __builtin_amdgcn_mfma_f32_16x16x32_bf16(                \
          fa[fm][ks], fb1[fn][ks], acc[qa][1][fm][fn], 0, 0, 0);                   \
  }                                                                                \
  __builtin_amdgcn_s_setprio(0);

template <int OUT_BF16, int BIAS_MODE, int KSPLIT>   // BIAS: 0 none, 1 col(split@2048), 2 row
__global__ __launch_bounds__(512, 2) void gemm256(
    const u16* __restrict__ A0p, const u16* __restrict__ B0p, void* __restrict__ D0p,
    const float* __restrict__ ba0, const float* __restrict__ bb0,
    const u16* __restrict__ A1p, const u16* __restrict__ B1p, void* __restrict__ D1p,
    const float* __restrict__ ba1, const float* __restrict__ bb1,
    long sk1, long sk2, long sk3,
    int zsplit, int K, int lda, int ldb, int ldd,
    long sA, long sB, long sD) {
  __shared__ __attribute__((aligned(128))) char sm[131072];
  // XCD-chunked swizzle (T1): bijective since nwg % 8 == 0 for all our launches.
  const int gx = gridDim.x, gy = gridDim.y;
  const int nwg = gx * gy * (int)gridDim.z;
  const int lin = blockIdx.x + gx * (blockIdx.y + gy * blockIdx.z);
  const int qch = nwg >> 3;
  int swzid = (lin & 7) * qch + (lin >> 3);
  const int bx = swzid % gx; swzid /= gx;
  const int by = swzid % gy;
  int zb = swzid / gy;
  int kh = 0;
  if (KSPLIT) { kh = zb >> 3; zb &= 7; }
  const bool s1 = (zb >= zsplit);
  const int zz = s1 ? zb - zsplit : zb;
  const u16* Ag = (s1 ? A1p : A0p) + (long)zz * sA + (long)kh * K;
  const u16* Bg = (s1 ? B1p : B0p) + (long)zz * sB + (long)kh * K;
  long khoff = 0;
  if (KSPLIT) { if (kh == 1) khoff = sk1; else if (kh == 2) khoff = sk2;
                else if (kh == 3) khoff = sk3; }
  char* Dg = (char*)(s1 ? D1p : D0p) + (long)zz * sD * (OUT_BF16 ? 2 : 4) + khoff;
  const float* ba = s1 ? ba1 : ba0;
  const float* bb = s1 ? bb1 : bb0;
  const int m0 = by * 256, n0 = bx * 256;
  const int t = threadIdx.x, w = t >> 6, l = t & 63;
  const int wr = w >> 2, wc = w & 3;             // 2x4 waves within a quadrant
  const int lm = l & 15, lk = l >> 4;
  const int swz = (l & 7) << 4;                  // read-side XOR: (row&7)<<4
  const int srow = l >> 3;
  const int scol = ((l & 7) ^ srow) << 3;        // inverse-swizzled source col (elems)
  int aoff[4], boff[2], kin[2];
#pragma unroll
  for (int fm = 0; fm < 4; ++fm) aoff[fm] = (wr * 64 + fm * 16 + lm) * 128;
#pragma unroll
  for (int fn = 0; fn < 2; ++fn) boff[fn] = (wc * 32 + fn * 16 + lm) * 128;
  kin[0] = (lk * 16) ^ swz;
  kin[1] = (64 + lk * 16) ^ swz;

  f32x4 acc[2][2][4][2] = {};
  bf16x8 fa[4][2], fb0[2][2], fb1[2][2];

  const int nt = K >> 6;                         // K-tiles of 64 (even for all our K)

  // prologue: buf0 full + b1A0,b1B0,b1B1; force buf0 (8 oldest), keep 6 in flight
  STG(Ag, lda, m0,       0, b0A0);
  STG(Bg, ldb, n0,       0, b0B0);
  STG(Bg, ldb, n0 + 128, 0, b0B1);
  STG(Ag, lda, m0 + 128, 0, b0A1);
  STG(Ag, lda, m0,       1, b1A0);
  STG(Bg, ldb, n0,       1, b1B0);
  STG(Bg, ldb, n0 + 128, 1, b1B1);
  VMW6;
  BAR_;

  for (int v = 0; v < nt; v += 2) {
    const int t2 = (v + 2 < nt) ? v + 2 : nt - 1;   // clamped (redundant tail restage ok)
    const int t3 = (v + 3 < nt) ? v + 3 : nt - 1;
    // P0v: tile v, quadrant-row 0
    STG(Ag, lda, m0 + 128, v + 1, b1A1);            // completes buf1 (read @P1w)
    RDA(b0A0); RDB(b0B0, fb0); RDB(b0B1, fb1);
    BAR_; LGK0; SB0; MMQ2(0);
    // P1v: tile v, quadrant-row 1 (fb0/fb1 persist); gate forces b1A1 + older
    STG(Ag, lda, m0, t2, b0A0);
    STG(Bg, ldb, n0, t2, b0B0);
    STG(Bg, ldb, n0 + 128, t2, b0B1);
    RDA(b0A1);
    VMW6;
    BAR_; LGK0; SB0; MMQ2(1);
    // P0w: tile v+1, quadrant-row 0
    STG(Ag, lda, m0 + 128, t2, b0A1);
    RDA(b1A0); RDB(b1B0, fb0); RDB(b1B1, fb1);
    BAR_; LGK0; SB0; MMQ2(0);
    // P1w: tile v+1, quadrant-row 1; gate forces b0A1(t2) + older
    STG(Ag, lda, m0, t3, b1A0);
    STG(Bg, ldb, n0, t3, b1B0);
    STG(Bg, ldb, n0 + 128, t3, b1B1);
    RDA(b1A1);
    VMW6;
    BAR_; LGK0; SB0; MMQ2(1);
  }

  // epilogue: C/D map col=lane&15, row=(lane>>4)*4+j (verified m89)
#pragma unroll
  for (int qa = 0; qa < 2; ++qa)
#pragma unroll
    for (int qb = 0; qb < 2; ++qb)
#pragma unroll
      for (int fm = 0; fm < 4; ++fm)
#pragma unroll
        for (int fn = 0; fn < 2; ++fn) {
          const int row0 = m0 + qa * 128 + wr * 64 + fm * 16 + lk * 4;
          const int col  = n0 + qb * 128 + wc * 32 + fn * 16 + lm;
          float cb = 0.f;
          if (BIAS_MODE == 1) cb = (col < 2048) ? ba[col] : bb[col - 2048];
          f32x4 vv = acc[qa][qb][fm][fn];
#pragma unroll
          for (int j = 0; j < 4; ++j) {
            float x = vv[j] + cb;
            if (BIAS_MODE == 2) x += ba[row0 + j];
            const long idx = (long)(row0 + j) * ldd + col;
            if (OUT_BF16) ((u16*)Dg)[idx] = f2bf(x);
            else          ((float*)Dg)[idx] = x;
          }
        }
}

// ---------- row softmax over 4 bf16 partials: softmax(alpha*sum) -> P bf16 ----------
__global__ void softmax_rows4(const u16* __restrict__ S0, const u16* __restrict__ S1,
                              const u16* __restrict__ S2, const u16* __restrict__ S3,
                              u16* __restrict__ P, float alpha) {
  const long row = blockIdx.x;
  const int t = threadIdx.x, l = t & 63, w = t >> 6;
  ushort4 a = ((const ushort4*)(S0 + row * 1024))[t];
  ushort4 b = ((const ushort4*)(S1 + row * 1024))[t];
  ushort4 c = ((const ushort4*)(S2 + row * 1024))[t];
  ushort4 d = ((const ushort4*)(S3 + row * 1024))[t];
  float v0 = bf2f(a.x) + bf2f(b.x) + bf2f(c.x) + bf2f(d.x);
  float v1 = bf2f(a.y) + bf2f(b.y) + bf2f(c.y) + bf2f(d.y);
  float v2 = bf2f(a.z) + bf2f(b.z) + bf2f(c.z) + bf2f(d.z);
  float v3 = bf2f(a.w) + bf2f(b.w) + bf2f(c.w) + bf2f(d.w);
  __shared__ float red[8];
  float m = fmaxf(fmaxf(v0, v1), fmaxf(v2, v3));
#pragma unroll
  for (int off = 32; off; off >>= 1) m = fmaxf(m, __shfl_xor(m, off));
  if (l == 0) red[w] = m;
  __syncthreads();
  m = fmaxf(fmaxf(red[0], red[1]), fmaxf(red[2], red[3]));
  float e0 = __expf((v0 - m) * alpha);
  float e1 = __expf((v1 - m) * alpha);
  float e2 = __expf((v2 - m) * alpha);
  float e3 = __expf((v3 - m) * alpha);
  float s = e0 + e1 + e2 + e3;
#pragma unroll
  for (int off = 32; off; off >>= 1) s += __shfl_xor(s, off);
  if (l == 0) red[4 + w] = s;
  __syncthreads();
  s = red[4] + red[5] + red[6] + red[7];
  const float inv = 1.0f / s;
  ushort4 o;
  o.x = f2bf(e0 * inv); o.y = f2bf(e1 * inv);
  o.z = f2bf(e2 * inv); o.w = f2bf(e3 * inv);
  ((ushort4*)(P + row * 1024))[t] = o;
}

// ---------- final: AW[b][d] = pv_d0+pv_d1 (f32); F_final = AW[b][0]+AW[b][1] ----------
__global__ void final_add2(const ushort4* __restrict__ p00, const ushort4* __restrict__ p01,
                           const ushort4* __restrict__ p10, const ushort4* __restrict__ p11,
                           float4* __restrict__ aw, float4* __restrict__ ff) {
  const long g = (long)blockIdx.x * 256 + threadIdx.x;   // 2,097,152 quads = [4][2048][256]
  const long b = g >> 19;
  const long rem = g & 524287;
  ushort4 x0 = p00[g], y0 = p01[g], x1 = p10[g], y1 = p11[g];
  float4 a0, a1, f;
  a0.x = bf2f(x0.x) + bf2f(y0.x); a0.y = bf2f(x0.y) + bf2f(y0.y);
  a0.z = bf2f(x0.z) + bf2f(y0.z); a0.w = bf2f(x0.w) + bf2f(y0.w);
  a1.x = bf2f(x1.x) + bf2f(y1.x); a1.y = bf2f(x1.y) + bf2f(y1.y);
  a1.z = bf2f(x1.z) + bf2f(y1.z); a1.w = bf2f(x1.w) + bf2f(y1.w);
  f.x = a0.x + a1.x; f.y = a0.y + a1.y; f.z = a0.z + a1.z; f.w = a0.w + a1.w;
  aw[(b * 2 + 0) * 524288 + rem] = a0;
  aw[(b * 2 + 1) * 524288 + rem] = a1;
  ff[b * 524288 + rem] = f;
}

// ---------- launch ----------
extern "C" void kernel_launch(void* const* d_in, const int* in_sizes, int n_in,
                              void* d_out, int out_size, void* d_ws, size_t ws_size,
                              hipStream_t stream) {
  (void)in_sizes; (void)n_in; (void)out_size; (void)ws_size;
  const float* F_rgb = (const float*)d_in[0];
  const float* F_ind = (const float*)d_in[1];
  const float* bq_rgb = (const float*)d_in[3];
  const float* bk_rgb = (const float*)d_in[5];
  const float* bv_rgb = (const float*)d_in[7];
  const float* bq_ind = (const float*)d_in[9];
  const float* bk_ind = (const float*)d_in[11];
  const float* bv_ind = (const float*)d_in[13];

  char* ws = (char*)d_ws;
  u16* FT_rgb  = (u16*)(ws);                        // [4][1024][2048] bf16
  u16* FT_ind  = (u16*)(ws + 16777216);
  u16* Wall    = (u16*)(ws + 33554432);             // 6x [2048][2048] bf16
  u16* Wqk_rgb = Wall;                              // [4096][2048] = Wq_rgb | Wk_rgb
  u16* Wqk_ind = (u16*)(ws + 50331648);
  u16* Wv_rgb  = (u16*)(ws + 67108864);
  u16* Wv_ind  = (u16*)(ws + 75497472);
  u16* QKT_rgb = (u16*)(ws + 83886080);             // [4][1024][4096]  Q|K
  u16* QKT_ind = (u16*)(ws + 117440512);
  u16* V_rgb   = (u16*)(ws + 150994944);            // [4][2048][1024]
  u16* V_ind   = (u16*)(ws + 167772160);
  u16* P       = (u16*)(ws + 184549376);            // [2][4][1024][1024] bf16
  // scores partials (each [2][4][1024][1024] bf16, 16.8 MB), kh0..kh3:
  u16* Skh0    = (u16*)(ws + 201326592);
  u16* Skh1    = (u16*)(ws + 218103808);            // ends 234881024 (< R1-proven 240 MB)
  u16* Skh2    = (u16*)(ws);                        // FT region dead after V conv
  u16* Skh3    = (u16*)(ws + 16777216);
  // PV partials (each [4][2048][1024] bf16, 16.8 MB): pv[dir][kh]
  u16* PV00    = (u16*)(ws + 201326592);            // scores partials dead after softmax
  u16* PV01    = (u16*)(ws + 218103808);
  u16* PV10    = (u16*)(ws);
  u16* PV11    = (u16*)(ws + 16777216);

  float* out       = (float*)d_out;
  float* out_final = out;                           // [4][2048][1024]
  float* out_Frgb  = out + 8388608;
  float* out_Find  = out + 16777216;
  float* AW        = out + 25165824;                // [4][2][2048][1024]

  // 1) prep: transpose+convert inputs (+identity passthrough) AND weight conversion
  prep<<<dim3(32, 64, 20), dim3(32, 8), 0, stream>>>(
      F_rgb, F_ind, FT_rgb, FT_ind, out_Frgb, out_Find,
      (const float*)d_in[2], (const float*)d_in[4],
      (const float*)d_in[8], (const float*)d_in[10],
      (const float*)d_in[6], (const float*)d_in[12], Wall);

  // 2) fused Q|K convs, both inputs in ONE 512-WG launch (col bias, split@2048)
  gemm256<1, 1, 0><<<dim3(16, 4, 8), 512, 0, stream>>>(
      FT_rgb, Wqk_rgb, QKT_rgb, bq_rgb, bk_rgb,
      FT_ind, Wqk_ind, QKT_ind, bq_ind, bk_ind,
      0L, 0L, 0L, 4, 2048, 2048, 2048, 4096, 2097152L, 0L, 4194304L);

  // 3) V convs (both inputs): V[c][n] = sum_k Wv[c][k] FT[n][k] + b[c]  (row bias)
  gemm256<1, 2, 0><<<dim3(4, 8, 8), 512, 0, stream>>>(
      Wv_rgb, FT_rgb, V_rgb, bv_rgb, bv_rgb,
      Wv_ind, FT_ind, V_ind, bv_ind, bv_ind,
      0L, 0L, 0L, 4, 2048, 2048, 2048, 1024, 0L, 2097152L, 2097152L);

  // 4) scores split-K x4 -> bf16 partials Skh0..3; 512 WGs (2/CU).
  //    kh byte offsets relative to Skh0, identical for both dir sets.
  gemm256<1, 0, 1><<<dim3(4, 4, 32), 512, 0, stream>>>(
      QKT_rgb, QKT_ind + 2048, Skh0, nullptr, nullptr,
      QKT_ind, QKT_rgb + 2048, Skh0 + 4194304, nullptr, nullptr,
      16777216L, -201326592L, -184549376L,
      4, 512, 4096, 4096, 1024, 4194304L, 4194304L, 1048576L);

  // 5) softmax over 4 partials (scale 1/sqrt(2048) folded in)
  softmax_rows4<<<8192, 256, 0, stream>>>(Skh0, Skh1, Skh2, Skh3, P,
                                          0.02209708691207961f);

  // 6) PV split-K x2 -> bf16 partials pv[dir][kh]; 512 WGs (2/CU).
  gemm256<1, 0, 1><<<dim3(4, 8, 16), 512, 0, stream>>>(
      V_ind, P, PV00, nullptr, nullptr,
      V_rgb, P + 4194304, PV10, nullptr, nullptr,
      16777216L, 0L, 0L,
      4, 512, 1024, 1024, 1024, 2097152L, 1048576L, 2097152L);

  // 7) AW = per-dir partial sums (f32); F_final = AW0 + AW1
  final_add2<<<8192, 256, 0, stream>>>(
      (const ushort4*)PV00, (const ushort4*)PV01,
      (const ushort4*)PV10, (const ushort4*)PV11,
      (float4*)AW, (float4*)out_final);
}